// Round 16
// baseline (57.318 us; speedup 1.0000x reference)
//
#include <hip/hip_runtime.h>
#include <math.h>

#define NB   4
#define HH   64
#define WW   64
#define CCH  256
#define GG   8
#define CGC  32
#define HI   66
#define NPIX 16384

typedef unsigned short ushort_t;
typedef __attribute__((ext_vector_type(8))) short short8;
typedef __attribute__((ext_vector_type(4))) float floatx4;

__device__ inline ushort_t f2bf(float f) {
    union { float f; unsigned u; } v; v.f = f;
    unsigned r = v.u + 0x7FFF + ((v.u >> 16) & 1);   // round-to-nearest-even
    return (ushort_t)(r >> 16);
}
__device__ inline float bf2f(ushort_t u) {
    union { unsigned u; float f; } v; v.u = ((unsigned)u) << 16; return v.f;
}

__device__ inline void gload_lds16(const ushort_t* g, ushort_t* l) {
    __builtin_amdgcn_global_load_lds(
        (const __attribute__((address_space(1))) void*)g,
        (__attribute__((address_space(3))) void*)l, 16, 0, 0);
}

// ---------------- 128x128 GEMM body (4 waves x 64x64), BK=64, dbuf ---------
// MODE 0: fp32 linear. MODE 1: bf16 xpad interior. MODE 2: bf16 linear.
template<int MODE>
__device__ __forceinline__
void gemm_body128(const ushort_t* __restrict__ A, const ushort_t* __restrict__ Bt,
                  const float* __restrict__ bias, void* __restrict__ outv,
                  ushort_t* As, ushort_t* Bs, int row0, int col0)
{
    const int tid  = threadIdx.x;
    const int lane = tid & 63, wid = tid >> 6;
    const int wr = wid >> 1, wc = wid & 1;
    const int q = lane >> 4, r = lane & 15;

    floatx4 acc[4][4] = {};

    auto stage = [&](int buf, int kt) {
        #pragma unroll
        for (int j = 0; j < 4; ++j) {              // A: 1024 granules
            int gi = j * 256 + tid;
            int arow = gi >> 3, gk = gi & 7;
            gload_lds16(A + (size_t)(row0 + arow) * 256 + kt * 64 + ((gk ^ (arow & 7)) * 8),
                        &As[buf * 128 * 64 + gi * 8]);
        }
        #pragma unroll
        for (int j = 0; j < 4; ++j) {              // B: 1024 granules
            int gi = j * 256 + tid;
            int brow = gi >> 3, gk = gi & 7;
            gload_lds16(Bt + (size_t)(col0 + brow) * 256 + kt * 64 + ((gk ^ (brow & 7)) * 8),
                        &Bs[buf * 128 * 64 + gi * 8]);
        }
    };

    stage(0, 0);
    __syncthreads();
    int cur = 0;
    #pragma unroll 1
    for (int kt = 0; kt < 4; ++kt) {
        if (kt < 3) stage(cur ^ 1, kt + 1);
        #pragma unroll
        for (int kk = 0; kk < 2; ++kk) {
            short8 af[4], bf[4];
            const int gsw = ((kk * 4 + q) ^ (r & 7)) * 8;
            #pragma unroll
            for (int m = 0; m < 4; ++m)
                af[m] = *(const short8*)&As[cur * 128 * 64 + (wr * 64 + m * 16 + r) * 64 + gsw];
            #pragma unroll
            for (int n = 0; n < 4; ++n)
                bf[n] = *(const short8*)&Bs[cur * 128 * 64 + (wc * 64 + n * 16 + r) * 64 + gsw];
            #pragma unroll
            for (int m = 0; m < 4; ++m)
                #pragma unroll
                for (int n = 0; n < 4; ++n)
                    acc[m][n] = __builtin_amdgcn_mfma_f32_16x16x32_bf16(
                                    af[m], bf[n], acc[m][n], 0, 0, 0);
        }
        __syncthreads();
        cur ^= 1;
    }

    #pragma unroll
    for (int m = 0; m < 4; ++m) {
        #pragma unroll
        for (int n = 0; n < 4; ++n) {
            #pragma unroll
            for (int j = 0; j < 4; ++j) {
                int row = row0 + wr * 64 + m * 16 + q * 4 + j;
                int col = col0 + wc * 64 + n * 16 + r;
                float v = acc[m][n][j] + bias[col];
                if (MODE == 1) {
                    int nn = row >> 12, hh = (row >> 6) & 63, www = row & 63;
                    ((ushort_t*)outv)[(size_t)((nn * HI + hh + 1) * HI + (www + 1)) * CCH + col] = f2bf(v);
                } else if (MODE == 2) {
                    ((ushort_t*)outv)[(size_t)row * 256 + col] = f2bf(v);
                } else {
                    ((float*)outv)[(size_t)row * 256 + col] = v;
                }
            }
        }
    }
}

__device__ __forceinline__ void swz256(int tbid, int& row0, int& col0) {
    int swz = (tbid & 7) * 32 + (tbid >> 3);      // nwg=256, bijective
    row0 = (swz >> 1) * 128;
    col0 = (swz & 1) * 128;
}

// ---------------- combined gemm1 + gemm2 (512 blocks, 128x128 tiles) --------
__global__ __launch_bounds__(256)
void gemm_in_off(const ushort_t* __restrict__ xb, const ushort_t* __restrict__ WtIn,
                 const float* __restrict__ in_b, ushort_t* __restrict__ xpadb,
                 const ushort_t* __restrict__ x1b, const ushort_t* __restrict__ W2t,
                 const float* __restrict__ b2, ushort_t* __restrict__ offm)
{
    __shared__ ushort_t As[2 * 128 * 64];   // 32 KB
    __shared__ ushort_t Bs[2 * 128 * 64];   // 32 KB
    int bid = blockIdx.x;
    int row0, col0;
    if (bid < 256) {
        swz256(bid, row0, col0);
        gemm_body128<1>(xb, WtIn, in_b, xpadb, As, Bs, row0, col0);
    } else {
        swz256(bid - 256, row0, col0);
        gemm_body128<2>(x1b, W2t, b2, offm, As, Bs, row0, col0);
    }
}

// ---------------- output projection GEMM (256 blocks, 128x128) --------------
__global__ __launch_bounds__(256)
void gemm_out(const ushort_t* __restrict__ A, const ushort_t* __restrict__ Bt,
              const float* __restrict__ bias, float* __restrict__ out)
{
    __shared__ ushort_t As[2 * 128 * 64];
    __shared__ ushort_t Bs[2 * 128 * 64];
    int row0, col0;
    swz256(blockIdx.x, row0, col0);
    gemm_body128<0>(A, Bt, bias, out, As, Bs, row0, col0);
}

// ---------------- merged: ring zero + weight pack + depthwise conv ----------
// W2t columns are GROUP-BLOCKED: col n = g*32 + j, j<18: offset(g,j),
// j in [18,27): mask logit(g,j-18), j>=27: zero pad.
__global__ __launch_bounds__(256)
void prep_dw(const float* __restrict__ x,
             const float* __restrict__ in_w, const float* __restrict__ out_w,
             const float* __restrict__ off_w, const float* __restrict__ mask_w,
             const float* __restrict__ off_b, const float* __restrict__ mask_b,
             const float* __restrict__ dw_k, const float* __restrict__ bn_g,
             const float* __restrict__ bn_b, const float* __restrict__ bn_m,
             const float* __restrict__ bn_v,
             ushort_t* __restrict__ xpadb,
             ushort_t* __restrict__ WtIn, ushort_t* __restrict__ WtOut,
             ushort_t* __restrict__ W2t, float* __restrict__ b2,
             ushort_t* __restrict__ x1b, ushort_t* __restrict__ xb)
{
    __shared__ float kT[9][256];   // tap-major dw_k, 9 KB
    const int bid = blockIdx.x;
    const int tid = threadIdx.x;

    if (bid < NB * 260) {
        int n = bid / 260, rp = bid % 260;
        int h, w;
        if (rp < 66)       { h = 0;              w = rp; }
        else if (rp < 132) { h = 65;             w = rp - 66; }
        else if (rp < 196) { h = 1 + (rp - 132); w = 0; }
        else               { h = 1 + (rp - 196); w = 65; }
        xpadb[(size_t)((n * HI + h) * HI + w) * CCH + tid] = 0;
        return;
    }
    if (bid < NB * 260 + 256) {
        int n = bid - NB * 260, k = tid;
        WtIn [n * 256 + k] = f2bf(in_w [k * 256 + n]);
        WtOut[n * 256 + k] = f2bf(out_w[k * 256 + n]);
        int g = n >> 5, j = n & 31;
        float w2 = (j < 18) ? off_w[k * 144 + g * 18 + j]
                 : (j < 27) ? mask_w[k * 72 + g * 9 + (j - 18)] : 0.f;
        W2t[n * 256 + k] = f2bf(w2);
        if (k == 0) b2[n] = (j < 18) ? off_b[g * 18 + j]
                          : (j < 27) ? mask_b[g * 9 + (j - 18)] : 0.f;
        return;
    }

    // ---------------- depthwise conv + BN + SiLU ----------------
    #pragma unroll
    for (int j = 0; j < 9; ++j) {
        int i = j * 256 + tid;             // 0..2303
        kT[i % 9][i / 9] = dw_k[i];
    }
    __syncthreads();

    const int lane = tid & 63, wvid = tid >> 6;
    const int pix = (bid - (NB * 260 + 256)) * 4 + wvid;
    const int n = pix >> 12, hw = pix & 4095, h = hw >> 6, w = hw & 63;
    const int c4 = lane << 2;

    const float4 cv = *reinterpret_cast<const float4*>(x + (size_t)pix * CCH + c4);
    ushort_t xo[4] = { f2bf(cv.x), f2bf(cv.y), f2bf(cv.z), f2bf(cv.w) };
    *reinterpret_cast<ushort4*>(xb + (size_t)pix * CCH + c4) = *reinterpret_cast<ushort4*>(xo);

    const float4 kc = *reinterpret_cast<const float4*>(&kT[4][c4]);
    float ax = cv.x * kc.x, ay = cv.y * kc.y, az = cv.z * kc.z, aw = cv.w * kc.w;

    #pragma unroll
    for (int tap = 0; tap < 9; ++tap) {
        if (tap == 4) continue;
        int hh = h + tap / 3 - 1, ww = w + tap % 3 - 1;
        if ((unsigned)hh < HH && (unsigned)ww < WW) {
            const float4 v = *reinterpret_cast<const float4*>(
                x + (size_t)((n * HH + hh) * WW + ww) * CCH + c4);
            const float4 kk = *reinterpret_cast<const float4*>(&kT[tap][c4]);
            ax += v.x * kk.x; ay += v.y * kk.y; az += v.z * kk.z; aw += v.w * kk.w;
        }
    }
    const float4 g4 = *reinterpret_cast<const float4*>(bn_g + c4);
    const float4 v4 = *reinterpret_cast<const float4*>(bn_v + c4);
    const float4 m4 = *reinterpret_cast<const float4*>(bn_m + c4);
    const float4 bb4 = *reinterpret_cast<const float4*>(bn_b + c4);
    float sx = g4.x * rsqrtf(v4.x + 1e-5f), sy = g4.y * rsqrtf(v4.y + 1e-5f);
    float sz = g4.z * rsqrtf(v4.z + 1e-5f), sw = g4.w * rsqrtf(v4.w + 1e-5f);
    float yx = (ax - m4.x) * sx + bb4.x, yy = (ay - m4.y) * sy + bb4.y;
    float yz = (az - m4.z) * sz + bb4.z, yw = (aw - m4.w) * sw + bb4.w;
    yx = yx / (1.f + __expf(-yx));
    yy = yy / (1.f + __expf(-yy));
    yz = yz / (1.f + __expf(-yz));
    yw = yw / (1.f + __expf(-yw));
    ushort_t o[4] = { f2bf(yx), f2bf(yy), f2bf(yz), f2bf(yw) };
    *reinterpret_cast<ushort4*>(x1b + (size_t)pix * CCH + c4) = *reinterpret_cast<ushort4*>(o);
}

// ---------------- DCNv3 core with LDS window staging ----------
// offm columns group-blocked: per pixel, group slice = offm[pix*256 + g*32],
// one contiguous 64B line (18 off, 9 logits, 5 pad).
__global__ __launch_bounds__(256)
void dcn_tile(const ushort_t* __restrict__ xpadb, const ushort_t* __restrict__ om,
              ushort_t* __restrict__ coreb)
{
    __shared__ ushort_t win[4 * 256 * 8];   // 16 KB
    const int tid = threadIdx.x;
    const int bid = blockIdx.x;
    const int tx = bid & 7, ty = (bid >> 3) & 7, g = (bid >> 6) & 7, n = bid >> 9;
    const int wx0 = tx * 8 - 3, wy0 = ty * 8 - 3;

    {
        const int dy = tid >> 4, dx = tid & 15;
        const int yy = wy0 + dy, xx = wx0 + dx;
        short8 v[4] = {{0,0,0,0,0,0,0,0},{0,0,0,0,0,0,0,0},
                       {0,0,0,0,0,0,0,0},{0,0,0,0,0,0,0,0}};
        if ((unsigned)yy < HI && (unsigned)xx < HI) {
            const ushort_t* src = xpadb + (size_t)((n * HI + yy) * HI + xx) * CCH + g * CGC;
            #pragma unroll
            for (int gr = 0; gr < 4; ++gr)
                v[gr] = *reinterpret_cast<const short8*>(src + gr * 8);
        }
        #pragma unroll
        for (int gr = 0; gr < 4; ++gr)
            *reinterpret_cast<short8*>(&win[(gr * 256 + tid) * 8]) = v[gr];
    }
    __syncthreads();

    const int px = tid >> 2, gr = tid & 3;
    const int h = ty * 8 + (px >> 3), w = tx * 8 + (px & 7);
    const int pix = (n << 12) | (h << 6) | w;
    const ushort_t* __restrict__ omp = om + (size_t)pix * 256 + g * 32;

    float lg9[9], mx = -1e30f;
    #pragma unroll
    for (int p = 0; p < 9; ++p) { lg9[p] = bf2f(omp[18 + p]); mx = fmaxf(mx, lg9[p]); }
    float s = 0.f;
    #pragma unroll
    for (int p = 0; p < 9; ++p) { lg9[p] = __expf(lg9[p] - mx); s += lg9[p]; }
    const float inv = 1.f / s;

    float acc[8] = {};
    #pragma unroll
    for (int p = 0; p < 9; ++p) {
        float ox = bf2f(omp[p * 2 + 0]);
        float oy = bf2f(omp[p * 2 + 1]);
        float xi = (float)(w + (p / 3)) + ox;
        float yi = (float)(h + (p % 3)) + oy;
        float x0f = floorf(xi), y0f = floorf(yi);
        int x0 = (int)x0f, y0 = (int)y0f;
        float fx = xi - x0f, fy = yi - y0f;
        float wgt = lg9[p] * inv;
        float cw[4] = { (1.f - fx) * (1.f - fy) * wgt, fx * (1.f - fy) * wgt,
                        (1.f - fx) * fy * wgt,         fx * fy * wgt };
        #pragma unroll
        for (int cr = 0; cr < 4; ++cr) {
            int xc = x0 + (cr & 1), yc = y0 + (cr >> 1);
            int sx = xc - wx0, sy = yc - wy0;
            float wc = cw[cr];
            if ((unsigned)sx < 16 && (unsigned)sy < 16) {
                short8 raw = *reinterpret_cast<const short8*>(
                    &win[(gr * 256 + sy * 16 + sx) * 8]);
                #pragma unroll
                for (int j = 0; j < 8; ++j) acc[j] += wc * bf2f((ushort_t)raw[j]);
            } else if ((unsigned)xc < HI && (unsigned)yc < HI) {
                short8 raw = *reinterpret_cast<const short8*>(
                    xpadb + (size_t)((n * HI + yc) * HI + xc) * CCH + g * CGC + gr * 8);
                #pragma unroll
                for (int j = 0; j < 8; ++j) acc[j] += wc * bf2f((ushort_t)raw[j]);
            }
        }
    }
    ushort_t o[8];
    #pragma unroll
    for (int j = 0; j < 8; ++j) o[j] = f2bf(acc[j]);
    *reinterpret_cast<short8*>(coreb + (size_t)pix * CCH + g * CGC + gr * 8) =
        *reinterpret_cast<short8*>(o);
}

extern "C" void kernel_launch(void* const* d_in, const int* in_sizes, int n_in,
                              void* d_out, int out_size, void* d_ws, size_t ws_size,
                              hipStream_t stream) {
    const float* x      = (const float*)d_in[0];
    const float* in_w   = (const float*)d_in[1];
    const float* in_b   = (const float*)d_in[2];
    const float* out_w  = (const float*)d_in[3];
    const float* out_b  = (const float*)d_in[4];
    const float* off_w  = (const float*)d_in[5];
    const float* off_b  = (const float*)d_in[6];
    const float* mask_w = (const float*)d_in[7];
    const float* mask_b = (const float*)d_in[8];
    const float* dw_k   = (const float*)d_in[9];
    const float* bn_g   = (const float*)d_in[10];
    const float* bn_b   = (const float*)d_in[11];
    const float* bn_m   = (const float*)d_in[12];
    const float* bn_v   = (const float*)d_in[13];

    ushort_t* xpadb = (ushort_t*)d_ws;                     // 4,460,544 us
    ushort_t* xb    = xpadb + 4460544;                     // 4,194,304 us
    ushort_t* x1b   = xb + 4194304;
    ushort_t* coreb = x1b + 4194304;
    ushort_t* offm  = coreb + 4194304;                     // 4,194,304 us (bf16)
    ushort_t* WtIn  = offm + 4194304;                      // 65,536 us
    ushort_t* WtOut = WtIn + 65536;
    ushort_t* W2t   = WtOut + 65536;
    float*    b2    = (float*)(W2t + 65536);               // 256 f

    // 1) ring zero + weight pack + depthwise conv
    prep_dw<<<NB * 260 + 256 + NPIX / 4, 256, 0, stream>>>(x,
        in_w, out_w, off_w, mask_w, off_b, mask_b,
        dw_k, bn_g, bn_b, bn_m, bn_v,
        xpadb, WtIn, WtOut, W2t, b2, x1b, xb);

    // 2) input projection + offset/mask projection (512 blocks, 128x128 tiles)
    gemm_in_off<<<512, 256, 0, stream>>>(xb, WtIn, in_b, xpadb, x1b, W2t, b2, offm);

    // 3) deformable sampling with LDS window staging (2048 blocks)
    dcn_tile<<<NB * GG * 64, 256, 0, stream>>>(xpadb, offm, coreb);

    // 4) output projection -> d_out (256 blocks, 128x128 tiles)
    gemm_out<<<256, 256, 0, stream>>>(coreb, WtOut, out_b, (float*)d_out);
}

// Round 17
// 56.504 us; speedup vs baseline: 1.0144x; 1.0144x over previous
//
#include <hip/hip_runtime.h>
#include <math.h>

#define NB   4
#define HH   64
#define WW   64
#define CCH  256
#define GG   8
#define CGC  32
#define HI   66
#define NPIX 16384

typedef unsigned short ushort_t;
typedef __attribute__((ext_vector_type(8))) short short8;
typedef __attribute__((ext_vector_type(4))) float floatx4;

__device__ inline ushort_t f2bf(float f) {
    union { float f; unsigned u; } v; v.f = f;
    unsigned r = v.u + 0x7FFF + ((v.u >> 16) & 1);   // round-to-nearest-even
    return (ushort_t)(r >> 16);
}
__device__ inline float bf2f(ushort_t u) {
    union { unsigned u; float f; } v; v.u = ((unsigned)u) << 16; return v.f;
}

__device__ inline void gload_lds16(const ushort_t* g, ushort_t* l) {
    __builtin_amdgcn_global_load_lds(
        (const __attribute__((address_space(1))) void*)g,
        (__attribute__((address_space(3))) void*)l, 16, 0, 0);
}

// ---------------- 128x64 GEMM body (4 waves x 32x64), BK=64, dbuf ----------
// MODE 0: fp32 linear. MODE 1: bf16 xpad interior. MODE 2: bf16 linear.
template<int MODE>
__device__ __forceinline__
void gemm_body(const ushort_t* __restrict__ A, const ushort_t* __restrict__ Bt,
               const float* __restrict__ bias, void* __restrict__ outv,
               ushort_t* As, ushort_t* Bs, int row0, int col0)
{
    const int tid  = threadIdx.x;
    const int lane = tid & 63, wid = tid >> 6;
    const int q = lane >> 4, r = lane & 15;

    floatx4 acc[2][4] = {};

    auto stage = [&](int buf, int kt) {
        #pragma unroll
        for (int j = 0; j < 4; ++j) {              // A: 1024 granules, 4/thread
            int gi = j * 256 + tid;
            int arow = gi >> 3, gk = gi & 7;
            gload_lds16(A + (size_t)(row0 + arow) * 256 + kt * 64 + ((gk ^ (arow & 7)) * 8),
                        &As[buf * 128 * 64 + gi * 8]);
        }
        #pragma unroll
        for (int j = 0; j < 2; ++j) {              // B: 512 granules, 2/thread
            int gi = j * 256 + tid;
            int brow = gi >> 3, gk = gi & 7;
            gload_lds16(Bt + (size_t)(col0 + brow) * 256 + kt * 64 + ((gk ^ (brow & 7)) * 8),
                        &Bs[buf * 64 * 64 + gi * 8]);
        }
    };

    stage(0, 0);
    __syncthreads();
    int cur = 0;
    #pragma unroll 1
    for (int kt = 0; kt < 4; ++kt) {
        if (kt < 3) stage(cur ^ 1, kt + 1);
        #pragma unroll
        for (int kk = 0; kk < 2; ++kk) {
            short8 af[2], bf[4];
            const int gsw = ((kk * 4 + q) ^ (r & 7)) * 8;
            #pragma unroll
            for (int m = 0; m < 2; ++m)
                af[m] = *(const short8*)&As[cur * 128 * 64 + (wid * 32 + m * 16 + r) * 64 + gsw];
            #pragma unroll
            for (int n = 0; n < 4; ++n)
                bf[n] = *(const short8*)&Bs[cur * 64 * 64 + (n * 16 + r) * 64 + gsw];
            #pragma unroll
            for (int m = 0; m < 2; ++m)
                #pragma unroll
                for (int n = 0; n < 4; ++n)
                    acc[m][n] = __builtin_amdgcn_mfma_f32_16x16x32_bf16(
                                    af[m], bf[n], acc[m][n], 0, 0, 0);
        }
        __syncthreads();
        cur ^= 1;
    }

    #pragma unroll
    for (int m = 0; m < 2; ++m) {
        #pragma unroll
        for (int n = 0; n < 4; ++n) {
            #pragma unroll
            for (int j = 0; j < 4; ++j) {
                int row = row0 + wid * 32 + m * 16 + q * 4 + j;
                int col = col0 + n * 16 + r;
                float v = acc[m][n][j] + bias[col];
                if (MODE == 1) {
                    int nn = row >> 12, hh = (row >> 6) & 63, www = row & 63;
                    ((ushort_t*)outv)[(size_t)((nn * HI + hh + 1) * HI + (www + 1)) * CCH + col] = f2bf(v);
                } else if (MODE == 2) {
                    ((ushort_t*)outv)[(size_t)row * 256 + col] = f2bf(v);
                } else {
                    ((float*)outv)[(size_t)row * 256 + col] = v;
                }
            }
        }
    }
}

// ---------------- 128x128 GEMM body (4 waves x 64x64), BK=64, dbuf ---------
template<int MODE>
__device__ __forceinline__
void gemm_body128(const ushort_t* __restrict__ A, const ushort_t* __restrict__ Bt,
                  const float* __restrict__ bias, void* __restrict__ outv,
                  ushort_t* As, ushort_t* Bs, int row0, int col0)
{
    const int tid  = threadIdx.x;
    const int lane = tid & 63, wid = tid >> 6;
    const int wr = wid >> 1, wc = wid & 1;
    const int q = lane >> 4, r = lane & 15;

    floatx4 acc[4][4] = {};

    auto stage = [&](int buf, int kt) {
        #pragma unroll
        for (int j = 0; j < 4; ++j) {              // A: 1024 granules
            int gi = j * 256 + tid;
            int arow = gi >> 3, gk = gi & 7;
            gload_lds16(A + (size_t)(row0 + arow) * 256 + kt * 64 + ((gk ^ (arow & 7)) * 8),
                        &As[buf * 128 * 64 + gi * 8]);
        }
        #pragma unroll
        for (int j = 0; j < 4; ++j) {              // B: 1024 granules
            int gi = j * 256 + tid;
            int brow = gi >> 3, gk = gi & 7;
            gload_lds16(Bt + (size_t)(col0 + brow) * 256 + kt * 64 + ((gk ^ (brow & 7)) * 8),
                        &Bs[buf * 128 * 64 + gi * 8]);
        }
    };

    stage(0, 0);
    __syncthreads();
    int cur = 0;
    #pragma unroll 1
    for (int kt = 0; kt < 4; ++kt) {
        if (kt < 3) stage(cur ^ 1, kt + 1);
        #pragma unroll
        for (int kk = 0; kk < 2; ++kk) {
            short8 af[4], bf[4];
            const int gsw = ((kk * 4 + q) ^ (r & 7)) * 8;
            #pragma unroll
            for (int m = 0; m < 4; ++m)
                af[m] = *(const short8*)&As[cur * 128 * 64 + (wr * 64 + m * 16 + r) * 64 + gsw];
            #pragma unroll
            for (int n = 0; n < 4; ++n)
                bf[n] = *(const short8*)&Bs[cur * 128 * 64 + (wc * 64 + n * 16 + r) * 64 + gsw];
            #pragma unroll
            for (int m = 0; m < 4; ++m)
                #pragma unroll
                for (int n = 0; n < 4; ++n)
                    acc[m][n] = __builtin_amdgcn_mfma_f32_16x16x32_bf16(
                                    af[m], bf[n], acc[m][n], 0, 0, 0);
        }
        __syncthreads();
        cur ^= 1;
    }

    #pragma unroll
    for (int m = 0; m < 4; ++m) {
        #pragma unroll
        for (int n = 0; n < 4; ++n) {
            #pragma unroll
            for (int j = 0; j < 4; ++j) {
                int row = row0 + wr * 64 + m * 16 + q * 4 + j;
                int col = col0 + wc * 64 + n * 16 + r;
                float v = acc[m][n][j] + bias[col];
                if (MODE == 1) {
                    int nn = row >> 12, hh = (row >> 6) & 63, www = row & 63;
                    ((ushort_t*)outv)[(size_t)((nn * HI + hh + 1) * HI + (www + 1)) * CCH + col] = f2bf(v);
                } else if (MODE == 2) {
                    ((ushort_t*)outv)[(size_t)row * 256 + col] = f2bf(v);
                } else {
                    ((float*)outv)[(size_t)row * 256 + col] = v;
                }
            }
        }
    }
}

__device__ __forceinline__ void swz512(int tbid, int& row0, int& col0) {
    int swz = (tbid & 7) * 64 + (tbid >> 3);      // nwg=512, bijective
    row0 = (swz >> 2) * 128;
    col0 = (swz & 3) * 64;
}
__device__ __forceinline__ void swz256(int tbid, int& row0, int& col0) {
    int swz = (tbid & 7) * 32 + (tbid >> 3);      // nwg=256, bijective
    row0 = (swz >> 1) * 128;
    col0 = (swz & 1) * 128;
}

// ---------------- combined gemm1 + gemm2 (512 blocks, 128x128 tiles) --------
__global__ __launch_bounds__(256)
void gemm_in_off(const ushort_t* __restrict__ xb, const ushort_t* __restrict__ WtIn,
                 const float* __restrict__ in_b, ushort_t* __restrict__ xpadb,
                 const ushort_t* __restrict__ x1b, const ushort_t* __restrict__ W2t,
                 const float* __restrict__ b2, ushort_t* __restrict__ offm)
{
    __shared__ ushort_t As[2 * 128 * 64];   // 32 KB
    __shared__ ushort_t Bs[2 * 128 * 64];   // 32 KB
    int bid = blockIdx.x;
    int row0, col0;
    if (bid < 256) {
        swz256(bid, row0, col0);
        gemm_body128<1>(xb, WtIn, in_b, xpadb, As, Bs, row0, col0);
    } else {
        swz256(bid - 256, row0, col0);
        gemm_body128<2>(x1b, W2t, b2, offm, As, Bs, row0, col0);
    }
}

// ---------------- output projection GEMM (512 blocks, 128x64) ---------------
__global__ __launch_bounds__(256)
void gemm_out(const ushort_t* __restrict__ A, const ushort_t* __restrict__ Bt,
              const float* __restrict__ bias, float* __restrict__ out)
{
    __shared__ ushort_t As[2 * 128 * 64];
    __shared__ ushort_t Bs[2 * 64 * 64];
    int row0, col0;
    swz512(blockIdx.x, row0, col0);
    gemm_body<0>(A, Bt, bias, out, As, Bs, row0, col0);
}

// ---------------- merged: ring zero + weight pack + depthwise conv ----------
// W2t columns GROUP-BLOCKED: col n = g*32 + j, j<18: offset(g,j),
// j in [18,27): mask logit(g,j-18), j>=27: zero pad.
__global__ __launch_bounds__(256)
void prep_dw(const float* __restrict__ x,
             const float* __restrict__ in_w, const float* __restrict__ out_w,
             const float* __restrict__ off_w, const float* __restrict__ mask_w,
             const float* __restrict__ off_b, const float* __restrict__ mask_b,
             const float* __restrict__ dw_k, const float* __restrict__ bn_g,
             const float* __restrict__ bn_b, const float* __restrict__ bn_m,
             const float* __restrict__ bn_v,
             ushort_t* __restrict__ xpadb,
             ushort_t* __restrict__ WtIn, ushort_t* __restrict__ WtOut,
             ushort_t* __restrict__ W2t, float* __restrict__ b2,
             ushort_t* __restrict__ x1b, ushort_t* __restrict__ xb)
{
    __shared__ float kT[9][256];   // tap-major dw_k, 9 KB
    const int bid = blockIdx.x;
    const int tid = threadIdx.x;

    if (bid < NB * 260) {
        int n = bid / 260, rp = bid % 260;
        int h, w;
        if (rp < 66)       { h = 0;              w = rp; }
        else if (rp < 132) { h = 65;             w = rp - 66; }
        else if (rp < 196) { h = 1 + (rp - 132); w = 0; }
        else               { h = 1 + (rp - 196); w = 65; }
        xpadb[(size_t)((n * HI + h) * HI + w) * CCH + tid] = 0;
        return;
    }
    if (bid < NB * 260 + 256) {
        int n = bid - NB * 260, k = tid;
        WtIn [n * 256 + k] = f2bf(in_w [k * 256 + n]);
        WtOut[n * 256 + k] = f2bf(out_w[k * 256 + n]);
        int g = n >> 5, j = n & 31;
        float w2 = (j < 18) ? off_w[k * 144 + g * 18 + j]
                 : (j < 27) ? mask_w[k * 72 + g * 9 + (j - 18)] : 0.f;
        W2t[n * 256 + k] = f2bf(w2);
        if (k == 0) b2[n] = (j < 18) ? off_b[g * 18 + j]
                          : (j < 27) ? mask_b[g * 9 + (j - 18)] : 0.f;
        return;
    }

    // ---------------- depthwise conv + BN + SiLU ----------------
    #pragma unroll
    for (int j = 0; j < 9; ++j) {
        int i = j * 256 + tid;             // 0..2303
        kT[i % 9][i / 9] = dw_k[i];
    }
    __syncthreads();

    const int lane = tid & 63, wvid = tid >> 6;
    const int pix = (bid - (NB * 260 + 256)) * 4 + wvid;
    const int n = pix >> 12, hw = pix & 4095, h = hw >> 6, w = hw & 63;
    const int c4 = lane << 2;

    const float4 cv = *reinterpret_cast<const float4*>(x + (size_t)pix * CCH + c4);
    ushort_t xo[4] = { f2bf(cv.x), f2bf(cv.y), f2bf(cv.z), f2bf(cv.w) };
    *reinterpret_cast<ushort4*>(xb + (size_t)pix * CCH + c4) = *reinterpret_cast<ushort4*>(xo);

    const float4 kc = *reinterpret_cast<const float4*>(&kT[4][c4]);
    float ax = cv.x * kc.x, ay = cv.y * kc.y, az = cv.z * kc.z, aw = cv.w * kc.w;

    #pragma unroll
    for (int tap = 0; tap < 9; ++tap) {
        if (tap == 4) continue;
        int hh = h + tap / 3 - 1, ww = w + tap % 3 - 1;
        if ((unsigned)hh < HH && (unsigned)ww < WW) {
            const float4 v = *reinterpret_cast<const float4*>(
                x + (size_t)((n * HH + hh) * WW + ww) * CCH + c4);
            const float4 kk = *reinterpret_cast<const float4*>(&kT[tap][c4]);
            ax += v.x * kk.x; ay += v.y * kk.y; az += v.z * kk.z; aw += v.w * kk.w;
        }
    }
    const float4 g4 = *reinterpret_cast<const float4*>(bn_g + c4);
    const float4 v4 = *reinterpret_cast<const float4*>(bn_v + c4);
    const float4 m4 = *reinterpret_cast<const float4*>(bn_m + c4);
    const float4 bb4 = *reinterpret_cast<const float4*>(bn_b + c4);
    float sx = g4.x * rsqrtf(v4.x + 1e-5f), sy = g4.y * rsqrtf(v4.y + 1e-5f);
    float sz = g4.z * rsqrtf(v4.z + 1e-5f), sw = g4.w * rsqrtf(v4.w + 1e-5f);
    float yx = (ax - m4.x) * sx + bb4.x, yy = (ay - m4.y) * sy + bb4.y;
    float yz = (az - m4.z) * sz + bb4.z, yw = (aw - m4.w) * sw + bb4.w;
    yx = yx / (1.f + __expf(-yx));
    yy = yy / (1.f + __expf(-yy));
    yz = yz / (1.f + __expf(-yz));
    yw = yw / (1.f + __expf(-yw));
    ushort_t o[4] = { f2bf(yx), f2bf(yy), f2bf(yz), f2bf(yw) };
    *reinterpret_cast<ushort4*>(x1b + (size_t)pix * CCH + c4) = *reinterpret_cast<ushort4*>(o);
}

// ---------------- DCNv3 core with LDS window staging ----------
// offm group-blocked: per pixel, group slice = offm[pix*256 + g*32] (64B line).
__global__ __launch_bounds__(256)
void dcn_tile(const ushort_t* __restrict__ xpadb, const ushort_t* __restrict__ om,
              ushort_t* __restrict__ coreb)
{
    __shared__ ushort_t win[4 * 256 * 8];   // 16 KB
    const int tid = threadIdx.x;
    const int bid = blockIdx.x;
    const int tx = bid & 7, ty = (bid >> 3) & 7, g = (bid >> 6) & 7, n = bid >> 9;
    const int wx0 = tx * 8 - 3, wy0 = ty * 8 - 3;

    {
        const int dy = tid >> 4, dx = tid & 15;
        const int yy = wy0 + dy, xx = wx0 + dx;
        short8 v[4] = {{0,0,0,0,0,0,0,0},{0,0,0,0,0,0,0,0},
                       {0,0,0,0,0,0,0,0},{0,0,0,0,0,0,0,0}};
        if ((unsigned)yy < HI && (unsigned)xx < HI) {
            const ushort_t* src = xpadb + (size_t)((n * HI + yy) * HI + xx) * CCH + g * CGC;
            #pragma unroll
            for (int gr = 0; gr < 4; ++gr)
                v[gr] = *reinterpret_cast<const short8*>(src + gr * 8);
        }
        #pragma unroll
        for (int gr = 0; gr < 4; ++gr)
            *reinterpret_cast<short8*>(&win[(gr * 256 + tid) * 8]) = v[gr];
    }
    __syncthreads();

    const int px = tid >> 2, gr = tid & 3;
    const int h = ty * 8 + (px >> 3), w = tx * 8 + (px & 7);
    const int pix = (n << 12) | (h << 6) | w;
    const ushort_t* __restrict__ omp = om + (size_t)pix * 256 + g * 32;

    float lg9[9], mx = -1e30f;
    #pragma unroll
    for (int p = 0; p < 9; ++p) { lg9[p] = bf2f(omp[18 + p]); mx = fmaxf(mx, lg9[p]); }
    float s = 0.f;
    #pragma unroll
    for (int p = 0; p < 9; ++p) { lg9[p] = __expf(lg9[p] - mx); s += lg9[p]; }
    const float inv = 1.f / s;

    float acc[8] = {};
    #pragma unroll
    for (int p = 0; p < 9; ++p) {
        float ox = bf2f(omp[p * 2 + 0]);
        float oy = bf2f(omp[p * 2 + 1]);
        float xi = (float)(w + (p / 3)) + ox;
        float yi = (float)(h + (p % 3)) + oy;
        float x0f = floorf(xi), y0f = floorf(yi);
        int x0 = (int)x0f, y0 = (int)y0f;
        float fx = xi - x0f, fy = yi - y0f;
        float wgt = lg9[p] * inv;
        float cw[4] = { (1.f - fx) * (1.f - fy) * wgt, fx * (1.f - fy) * wgt,
                        (1.f - fx) * fy * wgt,         fx * fy * wgt };
        #pragma unroll
        for (int cr = 0; cr < 4; ++cr) {
            int xc = x0 + (cr & 1), yc = y0 + (cr >> 1);
            int sx = xc - wx0, sy = yc - wy0;
            float wc = cw[cr];
            if ((unsigned)sx < 16 && (unsigned)sy < 16) {
                short8 raw = *reinterpret_cast<const short8*>(
                    &win[(gr * 256 + sy * 16 + sx) * 8]);
                #pragma unroll
                for (int j = 0; j < 8; ++j) acc[j] += wc * bf2f((ushort_t)raw[j]);
            } else if ((unsigned)xc < HI && (unsigned)yc < HI) {
                short8 raw = *reinterpret_cast<const short8*>(
                    xpadb + (size_t)((n * HI + yc) * HI + xc) * CCH + g * CGC + gr * 8);
                #pragma unroll
                for (int j = 0; j < 8; ++j) acc[j] += wc * bf2f((ushort_t)raw[j]);
            }
        }
    }
    ushort_t o[8];
    #pragma unroll
    for (int j = 0; j < 8; ++j) o[j] = f2bf(acc[j]);
    *reinterpret_cast<short8*>(coreb + (size_t)pix * CCH + g * CGC + gr * 8) =
        *reinterpret_cast<short8*>(o);
}

extern "C" void kernel_launch(void* const* d_in, const int* in_sizes, int n_in,
                              void* d_out, int out_size, void* d_ws, size_t ws_size,
                              hipStream_t stream) {
    const float* x      = (const float*)d_in[0];
    const float* in_w   = (const float*)d_in[1];
    const float* in_b   = (const float*)d_in[2];
    const float* out_w  = (const float*)d_in[3];
    const float* out_b  = (const float*)d_in[4];
    const float* off_w  = (const float*)d_in[5];
    const float* off_b  = (const float*)d_in[6];
    const float* mask_w = (const float*)d_in[7];
    const float* mask_b = (const float*)d_in[8];
    const float* dw_k   = (const float*)d_in[9];
    const float* bn_g   = (const float*)d_in[10];
    const float* bn_b   = (const float*)d_in[11];
    const float* bn_m   = (const float*)d_in[12];
    const float* bn_v   = (const float*)d_in[13];

    ushort_t* xpadb = (ushort_t*)d_ws;                     // 4,460,544 us
    ushort_t* xb    = xpadb + 4460544;                     // 4,194,304 us
    ushort_t* x1b   = xb + 4194304;
    ushort_t* coreb = x1b + 4194304;
    ushort_t* offm  = coreb + 4194304;                     // 4,194,304 us (bf16)
    ushort_t* WtIn  = offm + 4194304;                      // 65,536 us
    ushort_t* WtOut = WtIn + 65536;
    ushort_t* W2t   = WtOut + 65536;
    float*    b2    = (float*)(W2t + 65536);               // 256 f

    // 1) ring zero + weight pack + depthwise conv
    prep_dw<<<NB * 260 + 256 + NPIX / 4, 256, 0, stream>>>(x,
        in_w, out_w, off_w, mask_w, off_b, mask_b,
        dw_k, bn_g, bn_b, bn_m, bn_v,
        xpadb, WtIn, WtOut, W2t, b2, x1b, xb);

    // 2) input projection + offset/mask projection (512 blocks, 128x128 tiles)
    gemm_in_off<<<512, 256, 0, stream>>>(xb, WtIn, in_b, xpadb, x1b, W2t, b2, offm);

    // 3) deformable sampling with LDS window staging (2048 blocks)
    dcn_tile<<<NB * GG * 64, 256, 0, stream>>>(xpadb, offm, coreb);

    // 4) output projection -> d_out (512 blocks, 128x64 tiles)
    gemm_out<<<512, 256, 0, stream>>>(coreb, WtOut, out_b, (float*)d_out);
}

// Round 18
// 55.964 us; speedup vs baseline: 1.0242x; 1.0097x over previous
//
#include <hip/hip_runtime.h>
#include <math.h>

#define NB   4
#define HH   64
#define WW   64
#define CCH  256
#define GG   8
#define CGC  32
#define HI   66
#define NPIX 16384

typedef unsigned short ushort_t;
typedef __attribute__((ext_vector_type(8))) short short8;
typedef __attribute__((ext_vector_type(4))) float floatx4;

__device__ inline ushort_t f2bf(float f) {
    union { float f; unsigned u; } v; v.f = f;
    unsigned r = v.u + 0x7FFF + ((v.u >> 16) & 1);   // round-to-nearest-even
    return (ushort_t)(r >> 16);
}
__device__ inline float bf2f(ushort_t u) {
    union { unsigned u; float f; } v; v.u = ((unsigned)u) << 16; return v.f;
}

__device__ inline void gload_lds16(const ushort_t* g, ushort_t* l) {
    __builtin_amdgcn_global_load_lds(
        (const __attribute__((address_space(1))) void*)g,
        (__attribute__((address_space(3))) void*)l, 16, 0, 0);
}

// ---------------- 128x64 GEMM body (4 waves x 32x64), BK=64, dbuf ----------
// MODE 0: fp32 linear. MODE 1: bf16 xpad interior. MODE 2: bf16 linear.
template<int MODE>
__device__ __forceinline__
void gemm_body(const ushort_t* __restrict__ A, const ushort_t* __restrict__ Bt,
               const float* __restrict__ bias, void* __restrict__ outv,
               ushort_t* As, ushort_t* Bs, int row0, int col0)
{
    const int tid  = threadIdx.x;
    const int lane = tid & 63, wid = tid >> 6;
    const int q = lane >> 4, r = lane & 15;

    floatx4 acc[2][4] = {};

    auto stage = [&](int buf, int kt) {
        #pragma unroll
        for (int j = 0; j < 4; ++j) {              // A: 1024 granules, 4/thread
            int gi = j * 256 + tid;
            int arow = gi >> 3, gk = gi & 7;
            gload_lds16(A + (size_t)(row0 + arow) * 256 + kt * 64 + ((gk ^ (arow & 7)) * 8),
                        &As[buf * 128 * 64 + gi * 8]);
        }
        #pragma unroll
        for (int j = 0; j < 2; ++j) {              // B: 512 granules, 2/thread
            int gi = j * 256 + tid;
            int brow = gi >> 3, gk = gi & 7;
            gload_lds16(Bt + (size_t)(col0 + brow) * 256 + kt * 64 + ((gk ^ (brow & 7)) * 8),
                        &Bs[buf * 64 * 64 + gi * 8]);
        }
    };

    stage(0, 0);
    __syncthreads();
    int cur = 0;
    #pragma unroll 1
    for (int kt = 0; kt < 4; ++kt) {
        if (kt < 3) stage(cur ^ 1, kt + 1);
        #pragma unroll
        for (int kk = 0; kk < 2; ++kk) {
            short8 af[2], bf[4];
            const int gsw = ((kk * 4 + q) ^ (r & 7)) * 8;
            #pragma unroll
            for (int m = 0; m < 2; ++m)
                af[m] = *(const short8*)&As[cur * 128 * 64 + (wid * 32 + m * 16 + r) * 64 + gsw];
            #pragma unroll
            for (int n = 0; n < 4; ++n)
                bf[n] = *(const short8*)&Bs[cur * 64 * 64 + (n * 16 + r) * 64 + gsw];
            #pragma unroll
            for (int m = 0; m < 2; ++m)
                #pragma unroll
                for (int n = 0; n < 4; ++n)
                    acc[m][n] = __builtin_amdgcn_mfma_f32_16x16x32_bf16(
                                    af[m], bf[n], acc[m][n], 0, 0, 0);
        }
        __syncthreads();
        cur ^= 1;
    }

    #pragma unroll
    for (int m = 0; m < 2; ++m) {
        #pragma unroll
        for (int n = 0; n < 4; ++n) {
            #pragma unroll
            for (int j = 0; j < 4; ++j) {
                int row = row0 + wid * 32 + m * 16 + q * 4 + j;
                int col = col0 + n * 16 + r;
                float v = acc[m][n][j] + bias[col];
                if (MODE == 1) {
                    int nn = row >> 12, hh = (row >> 6) & 63, www = row & 63;
                    ((ushort_t*)outv)[(size_t)((nn * HI + hh + 1) * HI + (www + 1)) * CCH + col] = f2bf(v);
                } else if (MODE == 2) {
                    ((ushort_t*)outv)[(size_t)row * 256 + col] = f2bf(v);
                } else {
                    ((float*)outv)[(size_t)row * 256 + col] = v;
                }
            }
        }
    }
}

// ---------------- 128x128 GEMM body (4 waves x 64x64), BK=64, dbuf ---------
template<int MODE>
__device__ __forceinline__
void gemm_body128(const ushort_t* __restrict__ A, const ushort_t* __restrict__ Bt,
                  const float* __restrict__ bias, void* __restrict__ outv,
                  ushort_t* As, ushort_t* Bs, int row0, int col0)
{
    const int tid  = threadIdx.x;
    const int lane = tid & 63, wid = tid >> 6;
    const int wr = wid >> 1, wc = wid & 1;
    const int q = lane >> 4, r = lane & 15;

    floatx4 acc[4][4] = {};

    auto stage = [&](int buf, int kt) {
        #pragma unroll
        for (int j = 0; j < 4; ++j) {              // A: 1024 granules
            int gi = j * 256 + tid;
            int arow = gi >> 3, gk = gi & 7;
            gload_lds16(A + (size_t)(row0 + arow) * 256 + kt * 64 + ((gk ^ (arow & 7)) * 8),
                        &As[buf * 128 * 64 + gi * 8]);
        }
        #pragma unroll
        for (int j = 0; j < 4; ++j) {              // B: 1024 granules
            int gi = j * 256 + tid;
            int brow = gi >> 3, gk = gi & 7;
            gload_lds16(Bt + (size_t)(col0 + brow) * 256 + kt * 64 + ((gk ^ (brow & 7)) * 8),
                        &Bs[buf * 128 * 64 + gi * 8]);
        }
    };

    stage(0, 0);
    __syncthreads();
    int cur = 0;
    #pragma unroll 1
    for (int kt = 0; kt < 4; ++kt) {
        if (kt < 3) stage(cur ^ 1, kt + 1);
        #pragma unroll
        for (int kk = 0; kk < 2; ++kk) {
            short8 af[4], bf[4];
            const int gsw = ((kk * 4 + q) ^ (r & 7)) * 8;
            #pragma unroll
            for (int m = 0; m < 4; ++m)
                af[m] = *(const short8*)&As[cur * 128 * 64 + (wr * 64 + m * 16 + r) * 64 + gsw];
            #pragma unroll
            for (int n = 0; n < 4; ++n)
                bf[n] = *(const short8*)&Bs[cur * 128 * 64 + (wc * 64 + n * 16 + r) * 64 + gsw];
            #pragma unroll
            for (int m = 0; m < 4; ++m)
                #pragma unroll
                for (int n = 0; n < 4; ++n)
                    acc[m][n] = __builtin_amdgcn_mfma_f32_16x16x32_bf16(
                                    af[m], bf[n], acc[m][n], 0, 0, 0);
        }
        __syncthreads();
        cur ^= 1;
    }

    #pragma unroll
    for (int m = 0; m < 4; ++m) {
        #pragma unroll
        for (int n = 0; n < 4; ++n) {
            #pragma unroll
            for (int j = 0; j < 4; ++j) {
                int row = row0 + wr * 64 + m * 16 + q * 4 + j;
                int col = col0 + wc * 64 + n * 16 + r;
                float v = acc[m][n][j] + bias[col];
                if (MODE == 1) {
                    int nn = row >> 12, hh = (row >> 6) & 63, www = row & 63;
                    ((ushort_t*)outv)[(size_t)((nn * HI + hh + 1) * HI + (www + 1)) * CCH + col] = f2bf(v);
                } else if (MODE == 2) {
                    ((ushort_t*)outv)[(size_t)row * 256 + col] = f2bf(v);
                } else {
                    ((float*)outv)[(size_t)row * 256 + col] = v;
                }
            }
        }
    }
}

__device__ __forceinline__ void swz512(int tbid, int& row0, int& col0) {
    int swz = (tbid & 7) * 64 + (tbid >> 3);      // nwg=512, bijective
    row0 = (swz >> 2) * 128;
    col0 = (swz & 3) * 64;
}
__device__ __forceinline__ void swz256(int tbid, int& row0, int& col0) {
    int swz = (tbid & 7) * 32 + (tbid >> 3);      // nwg=256, bijective
    row0 = (swz >> 1) * 128;
    col0 = (swz & 1) * 128;
}

// ---------------- combined gemm1 + gemm2 (512 blocks, 128x128 tiles) --------
__global__ __launch_bounds__(256)
void gemm_in_off(const ushort_t* __restrict__ xb, const ushort_t* __restrict__ WtIn,
                 const float* __restrict__ in_b, ushort_t* __restrict__ xpadb,
                 const ushort_t* __restrict__ x1b, const ushort_t* __restrict__ W2t,
                 const float* __restrict__ b2, ushort_t* __restrict__ offm)
{
    __shared__ ushort_t As[2 * 128 * 64];   // 32 KB
    __shared__ ushort_t Bs[2 * 128 * 64];   // 32 KB
    int bid = blockIdx.x;
    int row0, col0;
    if (bid < 256) {
        swz256(bid, row0, col0);
        gemm_body128<1>(xb, WtIn, in_b, xpadb, As, Bs, row0, col0);
    } else {
        swz256(bid - 256, row0, col0);
        gemm_body128<2>(x1b, W2t, b2, offm, As, Bs, row0, col0);
    }
}

// ---------------- output projection GEMM (512 blocks, 128x64) ---------------
__global__ __launch_bounds__(256)
void gemm_out(const ushort_t* __restrict__ A, const ushort_t* __restrict__ Bt,
              const float* __restrict__ bias, float* __restrict__ out)
{
    __shared__ ushort_t As[2 * 128 * 64];
    __shared__ ushort_t Bs[2 * 64 * 64];
    int row0, col0;
    swz512(blockIdx.x, row0, col0);
    gemm_body<0>(A, Bt, bias, out, As, Bs, row0, col0);
}

// ---------------- merged: ring zero + weight pack + depthwise conv ----------
// W2t columns GROUP-BLOCKED: col n = g*32 + j, j<18: offset(g,j),
// j in [18,27): mask logit(g,j-18), j>=27: zero pad.
// dwconv blocks XCD-chunk-swizzled: each XCD owns a contiguous 2048-pixel
// strip (2 MB, L2-resident) so the 9-tap halo re-reads hit its own L2.
__global__ __launch_bounds__(256)
void prep_dw(const float* __restrict__ x,
             const float* __restrict__ in_w, const float* __restrict__ out_w,
             const float* __restrict__ off_w, const float* __restrict__ mask_w,
             const float* __restrict__ off_b, const float* __restrict__ mask_b,
             const float* __restrict__ dw_k, const float* __restrict__ bn_g,
             const float* __restrict__ bn_b, const float* __restrict__ bn_m,
             const float* __restrict__ bn_v,
             ushort_t* __restrict__ xpadb,
             ushort_t* __restrict__ WtIn, ushort_t* __restrict__ WtOut,
             ushort_t* __restrict__ W2t, float* __restrict__ b2,
             ushort_t* __restrict__ x1b, ushort_t* __restrict__ xb)
{
    __shared__ float kT[9][256];   // tap-major dw_k, 9 KB
    const int bid = blockIdx.x;
    const int tid = threadIdx.x;

    if (bid < NB * 260) {
        int n = bid / 260, rp = bid % 260;
        int h, w;
        if (rp < 66)       { h = 0;              w = rp; }
        else if (rp < 132) { h = 65;             w = rp - 66; }
        else if (rp < 196) { h = 1 + (rp - 132); w = 0; }
        else               { h = 1 + (rp - 196); w = 65; }
        xpadb[(size_t)((n * HI + h) * HI + w) * CCH + tid] = 0;
        return;
    }
    if (bid < NB * 260 + 256) {
        int n = bid - NB * 260, k = tid;
        WtIn [n * 256 + k] = f2bf(in_w [k * 256 + n]);
        WtOut[n * 256 + k] = f2bf(out_w[k * 256 + n]);
        int g = n >> 5, j = n & 31;
        float w2 = (j < 18) ? off_w[k * 144 + g * 18 + j]
                 : (j < 27) ? mask_w[k * 72 + g * 9 + (j - 18)] : 0.f;
        W2t[n * 256 + k] = f2bf(w2);
        if (k == 0) b2[n] = (j < 18) ? off_b[g * 18 + j]
                          : (j < 27) ? mask_b[g * 9 + (j - 18)] : 0.f;
        return;
    }

    // ---------------- depthwise conv + BN + SiLU ----------------
    #pragma unroll
    for (int j = 0; j < 9; ++j) {
        int i = j * 256 + tid;             // 0..2303
        kT[i % 9][i / 9] = dw_k[i];
    }
    __syncthreads();

    // XCD chunk swizzle over the 4096 dwconv blocks (4096 % 8 == 0)
    const int db  = bid - (NB * 260 + 256);
    const int sdb = (db & 7) * 512 + (db >> 3);

    const int lane = tid & 63, wvid = tid >> 6;
    const int pix = sdb * 4 + wvid;
    const int n = pix >> 12, hw = pix & 4095, h = hw >> 6, w = hw & 63;
    const int c4 = lane << 2;

    const float4 cv = *reinterpret_cast<const float4*>(x + (size_t)pix * CCH + c4);
    ushort_t xo[4] = { f2bf(cv.x), f2bf(cv.y), f2bf(cv.z), f2bf(cv.w) };
    *reinterpret_cast<ushort4*>(xb + (size_t)pix * CCH + c4) = *reinterpret_cast<ushort4*>(xo);

    const float4 kc = *reinterpret_cast<const float4*>(&kT[4][c4]);
    float ax = cv.x * kc.x, ay = cv.y * kc.y, az = cv.z * kc.z, aw = cv.w * kc.w;

    #pragma unroll
    for (int tap = 0; tap < 9; ++tap) {
        if (tap == 4) continue;
        int hh = h + tap / 3 - 1, ww = w + tap % 3 - 1;
        if ((unsigned)hh < HH && (unsigned)ww < WW) {
            const float4 v = *reinterpret_cast<const float4*>(
                x + (size_t)((n * HH + hh) * WW + ww) * CCH + c4);
            const float4 kk = *reinterpret_cast<const float4*>(&kT[tap][c4]);
            ax += v.x * kk.x; ay += v.y * kk.y; az += v.z * kk.z; aw += v.w * kk.w;
        }
    }
    const float4 g4 = *reinterpret_cast<const float4*>(bn_g + c4);
    const float4 v4 = *reinterpret_cast<const float4*>(bn_v + c4);
    const float4 m4 = *reinterpret_cast<const float4*>(bn_m + c4);
    const float4 bb4 = *reinterpret_cast<const float4*>(bn_b + c4);
    float sx = g4.x * rsqrtf(v4.x + 1e-5f), sy = g4.y * rsqrtf(v4.y + 1e-5f);
    float sz = g4.z * rsqrtf(v4.z + 1e-5f), sw = g4.w * rsqrtf(v4.w + 1e-5f);
    float yx = (ax - m4.x) * sx + bb4.x, yy = (ay - m4.y) * sy + bb4.y;
    float yz = (az - m4.z) * sz + bb4.z, yw = (aw - m4.w) * sw + bb4.w;
    yx = yx / (1.f + __expf(-yx));
    yy = yy / (1.f + __expf(-yy));
    yz = yz / (1.f + __expf(-yz));
    yw = yw / (1.f + __expf(-yw));
    ushort_t o[4] = { f2bf(yx), f2bf(yy), f2bf(yz), f2bf(yw) };
    *reinterpret_cast<ushort4*>(x1b + (size_t)pix * CCH + c4) = *reinterpret_cast<ushort4*>(o);
}

// ---------------- DCNv3 core with LDS window staging ----------
// offm group-blocked: per pixel, group slice = offm[pix*256 + g*32] (64B line).
// Blocks XCD-chunk-swizzled: each XCD owns complete (n,g) slices (279 KB,
// L2-resident) so overlapping 16x16 windows reuse its own L2.
__global__ __launch_bounds__(256)
void dcn_tile(const ushort_t* __restrict__ xpadb, const ushort_t* __restrict__ om,
              ushort_t* __restrict__ coreb)
{
    __shared__ ushort_t win[4 * 256 * 8];   // 16 KB
    const int tid = threadIdx.x;
    const int sbid = (blockIdx.x & 7) * 256 + (blockIdx.x >> 3);   // 2048 % 8 == 0
    const int tx = sbid & 7, ty = (sbid >> 3) & 7, g = (sbid >> 6) & 7, n = sbid >> 9;
    const int wx0 = tx * 8 - 3, wy0 = ty * 8 - 3;

    {
        const int dy = tid >> 4, dx = tid & 15;
        const int yy = wy0 + dy, xx = wx0 + dx;
        short8 v[4] = {{0,0,0,0,0,0,0,0},{0,0,0,0,0,0,0,0},
                       {0,0,0,0,0,0,0,0},{0,0,0,0,0,0,0,0}};
        if ((unsigned)yy < HI && (unsigned)xx < HI) {
            const ushort_t* src = xpadb + (size_t)((n * HI + yy) * HI + xx) * CCH + g * CGC;
            #pragma unroll
            for (int gr = 0; gr < 4; ++gr)
                v[gr] = *reinterpret_cast<const short8*>(src + gr * 8);
        }
        #pragma unroll
        for (int gr = 0; gr < 4; ++gr)
            *reinterpret_cast<short8*>(&win[(gr * 256 + tid) * 8]) = v[gr];
    }
    __syncthreads();

    const int px = tid >> 2, gr = tid & 3;
    const int h = ty * 8 + (px >> 3), w = tx * 8 + (px & 7);
    const int pix = (n << 12) | (h << 6) | w;
    const ushort_t* __restrict__ omp = om + (size_t)pix * 256 + g * 32;

    float lg9[9], mx = -1e30f;
    #pragma unroll
    for (int p = 0; p < 9; ++p) { lg9[p] = bf2f(omp[18 + p]); mx = fmaxf(mx, lg9[p]); }
    float s = 0.f;
    #pragma unroll
    for (int p = 0; p < 9; ++p) { lg9[p] = __expf(lg9[p] - mx); s += lg9[p]; }
    const float inv = 1.f / s;

    float acc[8] = {};
    #pragma unroll
    for (int p = 0; p < 9; ++p) {
        float ox = bf2f(omp[p * 2 + 0]);
        float oy = bf2f(omp[p * 2 + 1]);
        float xi = (float)(w + (p / 3)) + ox;
        float yi = (float)(h + (p % 3)) + oy;
        float x0f = floorf(xi), y0f = floorf(yi);
        int x0 = (int)x0f, y0 = (int)y0f;
        float fx = xi - x0f, fy = yi - y0f;
        float wgt = lg9[p] * inv;
        float cw[4] = { (1.f - fx) * (1.f - fy) * wgt, fx * (1.f - fy) * wgt,
                        (1.f - fx) * fy * wgt,         fx * fy * wgt };
        #pragma unroll
        for (int cr = 0; cr < 4; ++cr) {
            int xc = x0 + (cr & 1), yc = y0 + (cr >> 1);
            int sx = xc - wx0, sy = yc - wy0;
            float wc = cw[cr];
            if ((unsigned)sx < 16 && (unsigned)sy < 16) {
                short8 raw = *reinterpret_cast<const short8*>(
                    &win[(gr * 256 + sy * 16 + sx) * 8]);
                #pragma unroll
                for (int j = 0; j < 8; ++j) acc[j] += wc * bf2f((ushort_t)raw[j]);
            } else if ((unsigned)xc < HI && (unsigned)yc < HI) {
                short8 raw = *reinterpret_cast<const short8*>(
                    xpadb + (size_t)((n * HI + yc) * HI + xc) * CCH + g * CGC + gr * 8);
                #pragma unroll
                for (int j = 0; j < 8; ++j) acc[j] += wc * bf2f((ushort_t)raw[j]);
            }
        }
    }
    ushort_t o[8];
    #pragma unroll
    for (int j = 0; j < 8; ++j) o[j] = f2bf(acc[j]);
    *reinterpret_cast<short8*>(coreb + (size_t)pix * CCH + g * CGC + gr * 8) =
        *reinterpret_cast<short8*>(o);
}

extern "C" void kernel_launch(void* const* d_in, const int* in_sizes, int n_in,
                              void* d_out, int out_size, void* d_ws, size_t ws_size,
                              hipStream_t stream) {
    const float* x      = (const float*)d_in[0];
    const float* in_w   = (const float*)d_in[1];
    const float* in_b   = (const float*)d_in[2];
    const float* out_w  = (const float*)d_in[3];
    const float* out_b  = (const float*)d_in[4];
    const float* off_w  = (const float*)d_in[5];
    const float* off_b  = (const float*)d_in[6];
    const float* mask_w = (const float*)d_in[7];
    const float* mask_b = (const float*)d_in[8];
    const float* dw_k   = (const float*)d_in[9];
    const float* bn_g   = (const float*)d_in[10];
    const float* bn_b   = (const float*)d_in[11];
    const float* bn_m   = (const float*)d_in[12];
    const float* bn_v   = (const float*)d_in[13];

    ushort_t* xpadb = (ushort_t*)d_ws;                     // 4,460,544 us
    ushort_t* xb    = xpadb + 4460544;                     // 4,194,304 us
    ushort_t* x1b   = xb + 4194304;
    ushort_t* coreb = x1b + 4194304;
    ushort_t* offm  = coreb + 4194304;                     // 4,194,304 us (bf16)
    ushort_t* WtIn  = offm + 4194304;                      // 65,536 us
    ushort_t* WtOut = WtIn + 65536;
    ushort_t* W2t   = WtOut + 65536;
    float*    b2    = (float*)(W2t + 65536);               // 256 f

    // 1) ring zero + weight pack + depthwise conv (XCD-swizzled dwconv)
    prep_dw<<<NB * 260 + 256 + NPIX / 4, 256, 0, stream>>>(x,
        in_w, out_w, off_w, mask_w, off_b, mask_b,
        dw_k, bn_g, bn_b, bn_m, bn_v,
        xpadb, WtIn, WtOut, W2t, b2, x1b, xb);

    // 2) input projection + offset/mask projection (512 blocks, 128x128 tiles)
    gemm_in_off<<<512, 256, 0, stream>>>(xb, WtIn, in_b, xpadb, x1b, W2t, b2, offm);

    // 3) deformable sampling with LDS window staging (XCD-swizzled)
    dcn_tile<<<NB * GG * 64, 256, 0, stream>>>(xpadb, offm, coreb);

    // 4) output projection -> d_out (512 blocks, 128x64 tiles)
    gemm_out<<<512, 256, 0, stream>>>(coreb, WtOut, out_b, (float*)d_out);
}

// Round 19
// 55.951 us; speedup vs baseline: 1.0244x; 1.0002x over previous
//
#include <hip/hip_runtime.h>
#include <math.h>

#define NB   4
#define HH   64
#define WW   64
#define CCH  256
#define GG   8
#define CGC  32
#define HI   66
#define NPIX 16384

typedef unsigned short ushort_t;
typedef __attribute__((ext_vector_type(8))) short short8;
typedef __attribute__((ext_vector_type(4))) float floatx4;

__device__ inline ushort_t f2bf(float f) {
    union { float f; unsigned u; } v; v.f = f;
    unsigned r = v.u + 0x7FFF + ((v.u >> 16) & 1);   // round-to-nearest-even
    return (ushort_t)(r >> 16);
}
__device__ inline float bf2f(ushort_t u) {
    union { unsigned u; float f; } v; v.u = ((unsigned)u) << 16; return v.f;
}

__device__ inline void gload_lds16(const ushort_t* g, ushort_t* l) {
    __builtin_amdgcn_global_load_lds(
        (const __attribute__((address_space(1))) void*)g,
        (__attribute__((address_space(3))) void*)l, 16, 0, 0);
}

// ---------------- 128x64 GEMM body (4 waves x 32x64), BK=64, dbuf ----------
// MODE 0: fp32 linear. MODE 1: bf16 xpad interior. MODE 2: bf16 linear.
template<int MODE>
__device__ __forceinline__
void gemm_body(const ushort_t* __restrict__ A, const ushort_t* __restrict__ Bt,
               const float* __restrict__ bias, void* __restrict__ outv,
               ushort_t* As, ushort_t* Bs, int row0, int col0)
{
    const int tid  = threadIdx.x;
    const int lane = tid & 63, wid = tid >> 6;
    const int q = lane >> 4, r = lane & 15;

    floatx4 acc[2][4] = {};

    auto stage = [&](int buf, int kt) {
        #pragma unroll
        for (int j = 0; j < 4; ++j) {              // A: 1024 granules, 4/thread
            int gi = j * 256 + tid;
            int arow = gi >> 3, gk = gi & 7;
            gload_lds16(A + (size_t)(row0 + arow) * 256 + kt * 64 + ((gk ^ (arow & 7)) * 8),
                        &As[buf * 128 * 64 + gi * 8]);
        }
        #pragma unroll
        for (int j = 0; j < 2; ++j) {              // B: 512 granules, 2/thread
            int gi = j * 256 + tid;
            int brow = gi >> 3, gk = gi & 7;
            gload_lds16(Bt + (size_t)(col0 + brow) * 256 + kt * 64 + ((gk ^ (brow & 7)) * 8),
                        &Bs[buf * 64 * 64 + gi * 8]);
        }
    };

    stage(0, 0);
    __syncthreads();
    int cur = 0;
    #pragma unroll 1
    for (int kt = 0; kt < 4; ++kt) {
        if (kt < 3) stage(cur ^ 1, kt + 1);
        #pragma unroll
        for (int kk = 0; kk < 2; ++kk) {
            short8 af[2], bf[4];
            const int gsw = ((kk * 4 + q) ^ (r & 7)) * 8;
            #pragma unroll
            for (int m = 0; m < 2; ++m)
                af[m] = *(const short8*)&As[cur * 128 * 64 + (wid * 32 + m * 16 + r) * 64 + gsw];
            #pragma unroll
            for (int n = 0; n < 4; ++n)
                bf[n] = *(const short8*)&Bs[cur * 64 * 64 + (n * 16 + r) * 64 + gsw];
            #pragma unroll
            for (int m = 0; m < 2; ++m)
                #pragma unroll
                for (int n = 0; n < 4; ++n)
                    acc[m][n] = __builtin_amdgcn_mfma_f32_16x16x32_bf16(
                                    af[m], bf[n], acc[m][n], 0, 0, 0);
        }
        __syncthreads();
        cur ^= 1;
    }

    #pragma unroll
    for (int m = 0; m < 2; ++m) {
        #pragma unroll
        for (int n = 0; n < 4; ++n) {
            #pragma unroll
            for (int j = 0; j < 4; ++j) {
                int row = row0 + wid * 32 + m * 16 + q * 4 + j;
                int col = col0 + n * 16 + r;
                float v = acc[m][n][j] + bias[col];
                if (MODE == 1) {
                    int nn = row >> 12, hh = (row >> 6) & 63, www = row & 63;
                    ((ushort_t*)outv)[(size_t)((nn * HI + hh + 1) * HI + (www + 1)) * CCH + col] = f2bf(v);
                } else if (MODE == 2) {
                    ((ushort_t*)outv)[(size_t)row * 256 + col] = f2bf(v);
                } else {
                    ((float*)outv)[(size_t)row * 256 + col] = v;
                }
            }
        }
    }
}

// ---------------- 128x128 GEMM body (4 waves x 64x64), BK=64, dbuf ---------
// AFP32 = 1: A is fp32, converted to bf16 in-register while staging.
template<int MODE, int AFP32>
__device__ __forceinline__
void gemm_body128(const void* __restrict__ Av, const ushort_t* __restrict__ Bt,
                  const float* __restrict__ bias, void* __restrict__ outv,
                  ushort_t* As, ushort_t* Bs, int row0, int col0)
{
    const int tid  = threadIdx.x;
    const int lane = tid & 63, wid = tid >> 6;
    const int wr = wid >> 1, wc = wid & 1;
    const int q = lane >> 4, r = lane & 15;

    floatx4 acc[4][4] = {};

    auto stage = [&](int buf, int kt) {
        #pragma unroll
        for (int j = 0; j < 4; ++j) {              // A: 1024 granules
            int gi = j * 256 + tid;
            int arow = gi >> 3, gk = gi & 7;
            int src = kt * 64 + ((gk ^ (arow & 7)) * 8);
            if (AFP32) {
                const float* xa = (const float*)Av + (size_t)(row0 + arow) * 256 + src;
                float4 f0 = *reinterpret_cast<const float4*>(xa);
                float4 f1 = *reinterpret_cast<const float4*>(xa + 4);
                ushort_t cv[8] = { f2bf(f0.x), f2bf(f0.y), f2bf(f0.z), f2bf(f0.w),
                                   f2bf(f1.x), f2bf(f1.y), f2bf(f1.z), f2bf(f1.w) };
                *reinterpret_cast<short8*>(&As[buf * 128 * 64 + gi * 8]) =
                    *reinterpret_cast<short8*>(cv);
            } else {
                gload_lds16((const ushort_t*)Av + (size_t)(row0 + arow) * 256 + src,
                            &As[buf * 128 * 64 + gi * 8]);
            }
        }
        #pragma unroll
        for (int j = 0; j < 4; ++j) {              // B: 1024 granules
            int gi = j * 256 + tid;
            int brow = gi >> 3, gk = gi & 7;
            gload_lds16(Bt + (size_t)(col0 + brow) * 256 + kt * 64 + ((gk ^ (brow & 7)) * 8),
                        &Bs[buf * 128 * 64 + gi * 8]);
        }
    };

    stage(0, 0);
    __syncthreads();
    int cur = 0;
    #pragma unroll 1
    for (int kt = 0; kt < 4; ++kt) {
        if (kt < 3) stage(cur ^ 1, kt + 1);
        #pragma unroll
        for (int kk = 0; kk < 2; ++kk) {
            short8 af[4], bf[4];
            const int gsw = ((kk * 4 + q) ^ (r & 7)) * 8;
            #pragma unroll
            for (int m = 0; m < 4; ++m)
                af[m] = *(const short8*)&As[cur * 128 * 64 + (wr * 64 + m * 16 + r) * 64 + gsw];
            #pragma unroll
            for (int n = 0; n < 4; ++n)
                bf[n] = *(const short8*)&Bs[cur * 128 * 64 + (wc * 64 + n * 16 + r) * 64 + gsw];
            #pragma unroll
            for (int m = 0; m < 4; ++m)
                #pragma unroll
                for (int n = 0; n < 4; ++n)
                    acc[m][n] = __builtin_amdgcn_mfma_f32_16x16x32_bf16(
                                    af[m], bf[n], acc[m][n], 0, 0, 0);
        }
        __syncthreads();
        cur ^= 1;
    }

    #pragma unroll
    for (int m = 0; m < 4; ++m) {
        #pragma unroll
        for (int n = 0; n < 4; ++n) {
            #pragma unroll
            for (int j = 0; j < 4; ++j) {
                int row = row0 + wr * 64 + m * 16 + q * 4 + j;
                int col = col0 + wc * 64 + n * 16 + r;
                float v = acc[m][n][j] + bias[col];
                if (MODE == 1) {
                    int nn = row >> 12, hh = (row >> 6) & 63, www = row & 63;
                    ((ushort_t*)outv)[(size_t)((nn * HI + hh + 1) * HI + (www + 1)) * CCH + col] = f2bf(v);
                } else if (MODE == 2) {
                    ((ushort_t*)outv)[(size_t)row * 256 + col] = f2bf(v);
                } else {
                    ((float*)outv)[(size_t)row * 256 + col] = v;
                }
            }
        }
    }
}

__device__ __forceinline__ void swz512(int tbid, int& row0, int& col0) {
    int swz = (tbid & 7) * 64 + (tbid >> 3);      // nwg=512, bijective
    row0 = (swz >> 2) * 128;
    col0 = (swz & 3) * 64;
}
__device__ __forceinline__ void swz256(int tbid, int& row0, int& col0) {
    int swz = (tbid & 7) * 32 + (tbid >> 3);      // nwg=256, bijective
    row0 = (swz >> 1) * 128;
    col0 = (swz & 1) * 128;
}

// ---------------- combined gemm1 + gemm2 (512 blocks, 128x128 tiles) --------
// gemm1 half reads fp32 x directly (cvt-while-staging; no xb buffer).
__global__ __launch_bounds__(256)
void gemm_in_off(const float* __restrict__ x, const ushort_t* __restrict__ WtIn,
                 const float* __restrict__ in_b, ushort_t* __restrict__ xpadb,
                 const ushort_t* __restrict__ x1b, const ushort_t* __restrict__ W2t,
                 const float* __restrict__ b2, ushort_t* __restrict__ offm)
{
    __shared__ ushort_t As[2 * 128 * 64];   // 32 KB
    __shared__ ushort_t Bs[2 * 128 * 64];   // 32 KB
    int bid = blockIdx.x;
    int row0, col0;
    if (bid < 256) {
        swz256(bid, row0, col0);
        gemm_body128<1, 1>(x, WtIn, in_b, xpadb, As, Bs, row0, col0);
    } else {
        swz256(bid - 256, row0, col0);
        gemm_body128<2, 0>(x1b, W2t, b2, offm, As, Bs, row0, col0);
    }
}

// ---------------- output projection GEMM (512 blocks, 128x64) ---------------
__global__ __launch_bounds__(256)
void gemm_out(const ushort_t* __restrict__ A, const ushort_t* __restrict__ Bt,
              const float* __restrict__ bias, float* __restrict__ out)
{
    __shared__ ushort_t As[2 * 128 * 64];
    __shared__ ushort_t Bs[2 * 64 * 64];
    int row0, col0;
    swz512(blockIdx.x, row0, col0);
    gemm_body<0>(A, Bt, bias, out, As, Bs, row0, col0);
}

// ---------------- merged: ring zero + weight pack + depthwise conv ----------
// W2t columns GROUP-BLOCKED: col n = g*32 + j, j<18: offset(g,j),
// j in [18,27): mask logit(g,j-18), j>=27: zero pad.
// dwconv blocks XCD-chunk-swizzled (contiguous 2048-pixel strip per XCD).
__global__ __launch_bounds__(256)
void prep_dw(const float* __restrict__ x,
             const float* __restrict__ in_w, const float* __restrict__ out_w,
             const float* __restrict__ off_w, const float* __restrict__ mask_w,
             const float* __restrict__ off_b, const float* __restrict__ mask_b,
             const float* __restrict__ dw_k, const float* __restrict__ bn_g,
             const float* __restrict__ bn_b, const float* __restrict__ bn_m,
             const float* __restrict__ bn_v,
             ushort_t* __restrict__ xpadb,
             ushort_t* __restrict__ WtIn, ushort_t* __restrict__ WtOut,
             ushort_t* __restrict__ W2t, float* __restrict__ b2,
             ushort_t* __restrict__ x1b)
{
    __shared__ float kT[9][256];   // tap-major dw_k, 9 KB
    const int bid = blockIdx.x;
    const int tid = threadIdx.x;

    if (bid < NB * 260) {
        int n = bid / 260, rp = bid % 260;
        int h, w;
        if (rp < 66)       { h = 0;              w = rp; }
        else if (rp < 132) { h = 65;             w = rp - 66; }
        else if (rp < 196) { h = 1 + (rp - 132); w = 0; }
        else               { h = 1 + (rp - 196); w = 65; }
        xpadb[(size_t)((n * HI + h) * HI + w) * CCH + tid] = 0;
        return;
    }
    if (bid < NB * 260 + 256) {
        int n = bid - NB * 260, k = tid;
        WtIn [n * 256 + k] = f2bf(in_w [k * 256 + n]);
        WtOut[n * 256 + k] = f2bf(out_w[k * 256 + n]);
        int g = n >> 5, j = n & 31;
        float w2 = (j < 18) ? off_w[k * 144 + g * 18 + j]
                 : (j < 27) ? mask_w[k * 72 + g * 9 + (j - 18)] : 0.f;
        W2t[n * 256 + k] = f2bf(w2);
        if (k == 0) b2[n] = (j < 18) ? off_b[g * 18 + j]
                          : (j < 27) ? mask_b[g * 9 + (j - 18)] : 0.f;
        return;
    }

    // ---------------- depthwise conv + BN + SiLU ----------------
    #pragma unroll
    for (int j = 0; j < 9; ++j) {
        int i = j * 256 + tid;             // 0..2303
        kT[i % 9][i / 9] = dw_k[i];
    }
    __syncthreads();

    // XCD chunk swizzle over the 4096 dwconv blocks (4096 % 8 == 0)
    const int db  = bid - (NB * 260 + 256);
    const int sdb = (db & 7) * 512 + (db >> 3);

    const int lane = tid & 63, wvid = tid >> 6;
    const int pix = sdb * 4 + wvid;
    const int n = pix >> 12, hw = pix & 4095, h = hw >> 6, w = hw & 63;
    const int c4 = lane << 2;

    const float4 cv = *reinterpret_cast<const float4*>(x + (size_t)pix * CCH + c4);

    const float4 kc = *reinterpret_cast<const float4*>(&kT[4][c4]);
    float ax = cv.x * kc.x, ay = cv.y * kc.y, az = cv.z * kc.z, aw = cv.w * kc.w;

    #pragma unroll
    for (int tap = 0; tap < 9; ++tap) {
        if (tap == 4) continue;
        int hh = h + tap / 3 - 1, ww = w + tap % 3 - 1;
        if ((unsigned)hh < HH && (unsigned)ww < WW) {
            const float4 v = *reinterpret_cast<const float4*>(
                x + (size_t)((n * HH + hh) * WW + ww) * CCH + c4);
            const float4 kk = *reinterpret_cast<const float4*>(&kT[tap][c4]);
            ax += v.x * kk.x; ay += v.y * kk.y; az += v.z * kk.z; aw += v.w * kk.w;
        }
    }
    const float4 g4 = *reinterpret_cast<const float4*>(bn_g + c4);
    const float4 v4 = *reinterpret_cast<const float4*>(bn_v + c4);
    const float4 m4 = *reinterpret_cast<const float4*>(bn_m + c4);
    const float4 bb4 = *reinterpret_cast<const float4*>(bn_b + c4);
    float sx = g4.x * rsqrtf(v4.x + 1e-5f), sy = g4.y * rsqrtf(v4.y + 1e-5f);
    float sz = g4.z * rsqrtf(v4.z + 1e-5f), sw = g4.w * rsqrtf(v4.w + 1e-5f);
    float yx = (ax - m4.x) * sx + bb4.x, yy = (ay - m4.y) * sy + bb4.y;
    float yz = (az - m4.z) * sz + bb4.z, yw = (aw - m4.w) * sw + bb4.w;
    yx = yx / (1.f + __expf(-yx));
    yy = yy / (1.f + __expf(-yy));
    yz = yz / (1.f + __expf(-yz));
    yw = yw / (1.f + __expf(-yw));
    ushort_t o[4] = { f2bf(yx), f2bf(yy), f2bf(yz), f2bf(yw) };
    *reinterpret_cast<ushort4*>(x1b + (size_t)pix * CCH + c4) = *reinterpret_cast<ushort4*>(o);
}

// ---------------- DCNv3 core with LDS window staging ----------
// offm group-blocked: per pixel, group slice = offm[pix*256 + g*32] (64B line).
// Blocks XCD-chunk-swizzled: each XCD owns complete (n,g) slices.
__global__ __launch_bounds__(256)
void dcn_tile(const ushort_t* __restrict__ xpadb, const ushort_t* __restrict__ om,
              ushort_t* __restrict__ coreb)
{
    __shared__ ushort_t win[4 * 256 * 8];   // 16 KB
    const int tid = threadIdx.x;
    const int sbid = (blockIdx.x & 7) * 256 + (blockIdx.x >> 3);   // 2048 % 8 == 0
    const int tx = sbid & 7, ty = (sbid >> 3) & 7, g = (sbid >> 6) & 7, n = sbid >> 9;
    const int wx0 = tx * 8 - 3, wy0 = ty * 8 - 3;

    {
        const int dy = tid >> 4, dx = tid & 15;
        const int yy = wy0 + dy, xx = wx0 + dx;
        short8 v[4] = {{0,0,0,0,0,0,0,0},{0,0,0,0,0,0,0,0},
                       {0,0,0,0,0,0,0,0},{0,0,0,0,0,0,0,0}};
        if ((unsigned)yy < HI && (unsigned)xx < HI) {
            const ushort_t* src = xpadb + (size_t)((n * HI + yy) * HI + xx) * CCH + g * CGC;
            #pragma unroll
            for (int gr = 0; gr < 4; ++gr)
                v[gr] = *reinterpret_cast<const short8*>(src + gr * 8);
        }
        #pragma unroll
        for (int gr = 0; gr < 4; ++gr)
            *reinterpret_cast<short8*>(&win[(gr * 256 + tid) * 8]) = v[gr];
    }
    __syncthreads();

    const int px = tid >> 2, gr = tid & 3;
    const int h = ty * 8 + (px >> 3), w = tx * 8 + (px & 7);
    const int pix = (n << 12) | (h << 6) | w;
    const ushort_t* __restrict__ omp = om + (size_t)pix * 256 + g * 32;

    float lg9[9], mx = -1e30f;
    #pragma unroll
    for (int p = 0; p < 9; ++p) { lg9[p] = bf2f(omp[18 + p]); mx = fmaxf(mx, lg9[p]); }
    float s = 0.f;
    #pragma unroll
    for (int p = 0; p < 9; ++p) { lg9[p] = __expf(lg9[p] - mx); s += lg9[p]; }
    const float inv = 1.f / s;

    float acc[8] = {};
    #pragma unroll
    for (int p = 0; p < 9; ++p) {
        float ox = bf2f(omp[p * 2 + 0]);
        float oy = bf2f(omp[p * 2 + 1]);
        float xi = (float)(w + (p / 3)) + ox;
        float yi = (float)(h + (p % 3)) + oy;
        float x0f = floorf(xi), y0f = floorf(yi);
        int x0 = (int)x0f, y0 = (int)y0f;
        float fx = xi - x0f, fy = yi - y0f;
        float wgt = lg9[p] * inv;
        float cw[4] = { (1.f - fx) * (1.f - fy) * wgt, fx * (1.f - fy) * wgt,
                        (1.f - fx) * fy * wgt,         fx * fy * wgt };
        #pragma unroll
        for (int cr = 0; cr < 4; ++cr) {
            int xc = x0 + (cr & 1), yc = y0 + (cr >> 1);
            int sx = xc - wx0, sy = yc - wy0;
            float wc = cw[cr];
            if ((unsigned)sx < 16 && (unsigned)sy < 16) {
                short8 raw = *reinterpret_cast<const short8*>(
                    &win[(gr * 256 + sy * 16 + sx) * 8]);
                #pragma unroll
                for (int j = 0; j < 8; ++j) acc[j] += wc * bf2f((ushort_t)raw[j]);
            } else if ((unsigned)xc < HI && (unsigned)yc < HI) {
                short8 raw = *reinterpret_cast<const short8*>(
                    xpadb + (size_t)((n * HI + yc) * HI + xc) * CCH + g * CGC + gr * 8);
                #pragma unroll
                for (int j = 0; j < 8; ++j) acc[j] += wc * bf2f((ushort_t)raw[j]);
            }
        }
    }
    ushort_t o[8];
    #pragma unroll
    for (int j = 0; j < 8; ++j) o[j] = f2bf(acc[j]);
    *reinterpret_cast<short8*>(coreb + (size_t)pix * CCH + g * CGC + gr * 8) =
        *reinterpret_cast<short8*>(o);
}

extern "C" void kernel_launch(void* const* d_in, const int* in_sizes, int n_in,
                              void* d_out, int out_size, void* d_ws, size_t ws_size,
                              hipStream_t stream) {
    const float* x      = (const float*)d_in[0];
    const float* in_w   = (const float*)d_in[1];
    const float* in_b   = (const float*)d_in[2];
    const float* out_w  = (const float*)d_in[3];
    const float* out_b  = (const float*)d_in[4];
    const float* off_w  = (const float*)d_in[5];
    const float* off_b  = (const float*)d_in[6];
    const float* mask_w = (const float*)d_in[7];
    const float* mask_b = (const float*)d_in[8];
    const float* dw_k   = (const float*)d_in[9];
    const float* bn_g   = (const float*)d_in[10];
    const float* bn_b   = (const float*)d_in[11];
    const float* bn_m   = (const float*)d_in[12];
    const float* bn_v   = (const float*)d_in[13];

    ushort_t* xpadb = (ushort_t*)d_ws;                     // 4,460,544 us
    ushort_t* x1b   = xpadb + 4460544;                     // 4,194,304 us
    ushort_t* coreb = x1b + 4194304;
    ushort_t* offm  = coreb + 4194304;                     // 4,194,304 us (bf16)
    ushort_t* WtIn  = offm + 4194304;                      // 65,536 us
    ushort_t* WtOut = WtIn + 65536;
    ushort_t* W2t   = WtOut + 65536;
    float*    b2    = (float*)(W2t + 65536);               // 256 f

    // 1) ring zero + weight pack + depthwise conv (XCD-swizzled dwconv)
    prep_dw<<<NB * 260 + 256 + NPIX / 4, 256, 0, stream>>>(x,
        in_w, out_w, off_w, mask_w, off_b, mask_b,
        dw_k, bn_g, bn_b, bn_m, bn_v,
        xpadb, WtIn, WtOut, W2t, b2, x1b);

    // 2) input projection (fp32 A, cvt-while-staging) + offset/mask projection
    gemm_in_off<<<512, 256, 0, stream>>>(x, WtIn, in_b, xpadb, x1b, W2t, b2, offm);

    // 3) deformable sampling with LDS window staging (XCD-swizzled)
    dcn_tile<<<NB * GG * 64, 256, 0, stream>>>(xpadb, offm, coreb);

    // 4) output projection -> d_out (512 blocks, 128x64 tiles)
    gemm_out<<<512, 256, 0, stream>>>(coreb, WtOut, out_b, (float*)d_out);
}